// Round 3
// baseline (121.756 us; speedup 1.0000x reference)
//
#include <hip/hip_runtime.h>
#include <hip/hip_bf16.h>

typedef short bf16x8 __attribute__((ext_vector_type(8)));
typedef short bf16x4 __attribute__((ext_vector_type(4)));
typedef float f32x4  __attribute__((ext_vector_type(4)));

__device__ __forceinline__ unsigned short f2bf(float f) {
    union { float fv; unsigned int u; } v; v.fv = f;
    unsigned int r = v.u + 0x7FFFu + ((v.u >> 16) & 1u);
    return (unsigned short)(r >> 16);
}

__device__ __forceinline__ void gload16(const short* g, short* l) {
    __builtin_amdgcn_global_load_lds(
        (const __attribute__((address_space(1))) void*)g,
        (__attribute__((address_space(3))) void*)l, 16, 0, 0);
}

// ---- convert x f32 -> bf16, 8 elems/thread ----
__global__ __launch_bounds__(256) void cvt_x(
    const float* __restrict__ x, short* __restrict__ xb)
{
    size_t i = ((size_t)blockIdx.x * 256 + threadIdx.x) * 8;
    f32x4 a = *(const f32x4*)(x + i);
    f32x4 b = *(const f32x4*)(x + i + 4);
    bf16x8 s;
    #pragma unroll
    for (int e = 0; e < 4; ++e) { s[e] = (short)f2bf(a[e]); s[4 + e] = (short)f2bf(b[e]); }
    *(bf16x8*)(xb + i) = s;
}

// ---- prep: transpose + convert weights to bf16 [N][K] ----
__global__ __launch_bounds__(256) void prep_w(
    const float* __restrict__ Wqkv, const float* __restrict__ Wout,
    short* __restrict__ Wqkvt, short* __restrict__ Woutt)
{
    int idx = blockIdx.x * 256 + threadIdx.x;   // 0 .. 786431
    int n = idx >> 9, k = idx & 511;
    Wqkvt[idx] = (short)f2bf(Wqkv[(size_t)k * 1536 + n]);
    if (idx < 512 * 512) {
        Woutt[idx] = (short)f2bf(Wout[(size_t)k * 512 + n]);
    }
}

// ---- GEMM, 8-phase 256x256 template: C = A[M,K] * Bt[N,K]^T ----
// 512 thr = 8 waves (2M x 4N), per-wave 128x64 out, BK=64, dbuf LDS 128KB.
// LDS chunk-swizzle: slot(row, c) holds global chunk c ^ (row&7)  (involution,
// applied on the global source for global_load_lds and on the ds_read addr).
template<int F32OUT>
__global__ __launch_bounds__(512, 2) void gemm8p(
    const short* __restrict__ A, const short* __restrict__ Bt,
    short* __restrict__ Cb, float* __restrict__ Cf, const float* __restrict__ bias,
    int M, int N, int K)
{
    __shared__ short lds[2][32768];   // [buf][ A 256*64 | B 256*64 ]
    const int t    = threadIdx.x;
    const int lane = t & 63;
    const int wid  = t >> 6;
    const int l15  = lane & 15;
    const int lg   = lane >> 4;
    const int m0 = blockIdx.x * 256;
    const int n0 = blockIdx.y * 256;
    const int wr = wid >> 2;          // 0..1  (M)
    const int wc = wid & 3;           // 0..3  (N)
    const int R0 = wr * 128;
    const int C0 = wc * 64;

    // staging: half-tile h (0:A rows0-127, 1:A rows128-255, 2:B0, 3:B1)
    // wave wid covers rows wid*16 + j*8 + (lane>>3), j=0,1.
    // swizzled global col chunk = (lane&7) ^ ((lane>>3)&7)
    const int srow = wid * 16 + (lane >> 3);
    const int scol = 8 * ((lane & 7) ^ ((lane >> 3) & 7));

    // swizzled read chunk offsets (bytes): chunk(kk) = (kk*4+lg) ^ (l15&7)
    const int c0 = ((lg)     ^ (l15 & 7)) * 16;
    const int c1 = ((4 + lg) ^ (l15 & 7)) * 16;

    f32x4 acc[8][4];
    #pragma unroll
    for (int i = 0; i < 8; ++i)
        #pragma unroll
        for (int j = 0; j < 4; ++j)
            acc[i][j] = f32x4{0.f, 0.f, 0.f, 0.f};

    const int NT = K >> 6;

    // stage one half-tile of K-tile tk into buffer buf
    auto stage_half = [&](int buf, int h, int tk) {
        const short* src = (h < 2) ? A : Bt;
        const int rowbase = (h < 2) ? (m0 + h * 128) : (n0 + (h - 2) * 128);
        short* dst = &lds[buf][h * 8192];
        #pragma unroll
        for (int j = 0; j < 2; ++j) {
            gload16(src + (size_t)(rowbase + srow + j * 8) * K + tk * 64 + scol,
                    dst + (wid * 16 + j * 8) * 64);
        }
    };

    // prologue: stage tile 0 fully
    #pragma unroll
    for (int h = 0; h < 4; ++h) stage_half(0, h, 0);
    asm volatile("s_waitcnt vmcnt(0)" ::: "memory");
    __builtin_amdgcn_s_barrier();

    bf16x8 bgs[2][2];   // B frags, reused across the two qm-phases of a qn

#define PHASE(QM, QN, PH, LOADB)                                              \
    {                                                                         \
        const char* lp = (const char*)lds[cur];                               \
        bf16x8 af[4][2];                                                      \
        _Pragma("unroll")                                                     \
        for (int mi = 0; mi < 4; ++mi) {                                      \
            const int rb = (R0 + QM * 64 + mi * 16 + l15) * 128;              \
            af[mi][0] = *(const bf16x8*)(lp + rb + c0);                       \
            af[mi][1] = *(const bf16x8*)(lp + rb + c1);                       \
        }                                                                     \
        if (LOADB) {                                                          \
            _Pragma("unroll")                                                 \
            for (int ni = 0; ni < 2; ++ni) {                                  \
                const int nb = 32768 + (C0 + QN * 32 + ni * 16 + l15) * 128;  \
                bgs[ni][0] = *(const bf16x8*)(lp + nb + c0);                  \
                bgs[ni][1] = *(const bf16x8*)(lp + nb + c1);                  \
            }                                                                 \
        }                                                                     \
        if (tk + 1 < NT) stage_half(cur ^ 1, PH, tk + 1);                     \
        __builtin_amdgcn_s_barrier();                                         \
        __builtin_amdgcn_s_setprio(1);                                        \
        _Pragma("unroll")                                                     \
        for (int kk = 0; kk < 2; ++kk)                                        \
            _Pragma("unroll")                                                 \
            for (int mi = 0; mi < 4; ++mi)                                    \
                _Pragma("unroll")                                             \
                for (int ni = 0; ni < 2; ++ni)                                \
                    acc[QM * 4 + mi][QN * 2 + ni] =                           \
                        __builtin_amdgcn_mfma_f32_16x16x32_bf16(              \
                            af[mi][kk], bgs[ni][kk],                          \
                            acc[QM * 4 + mi][QN * 2 + ni], 0, 0, 0);          \
        __builtin_amdgcn_s_setprio(0);                                        \
        if (PH == 3) asm volatile("s_waitcnt vmcnt(0)" ::: "memory");         \
        __builtin_amdgcn_s_barrier();                                         \
    }

    for (int tk = 0; tk < NT; ++tk) {
        const int cur = tk & 1;
        PHASE(0, 0, 0, 1)
        PHASE(1, 0, 1, 0)
        PHASE(0, 1, 2, 1)
        PHASE(1, 1, 3, 0)
    }
#undef PHASE

    // epilogue
    #pragma unroll
    for (int mi8 = 0; mi8 < 8; ++mi8) {
        #pragma unroll
        for (int ni4 = 0; ni4 < 4; ++ni4) {
            const int col = n0 + C0 + ni4 * 16 + l15;
            #pragma unroll
            for (int r = 0; r < 4; ++r) {
                const int rowi = m0 + R0 + mi8 * 16 + 4 * lg + r;
                if constexpr (F32OUT) {
                    Cf[(size_t)rowi * N + col] = acc[mi8][ni4][r] + bias[col];
                } else {
                    Cb[(size_t)rowi * N + col] = (short)f2bf(acc[mi8][ni4][r]);
                }
            }
        }
    }
}

// ---- fused attention: one block per (b*p, head); 8 waves x 64 q-rows ----
__global__ __launch_bounds__(512) void attn_kernel(
    const short* __restrict__ qkv, short* __restrict__ attn_out)
{
    __shared__ short Kl[64][72];   // K tile  [kv][d], stride 144B
    __shared__ short Vt[64][76];   // V^T tile [d][kv], stride 152B (conflict fix)
    const int t    = threadIdx.x;
    const int lane = t & 63;
    const int wid  = t >> 6;
    const int l15  = lane & 15;
    const int lg   = lane >> 4;
    const int bph = blockIdx.x;
    const int bp = bph >> 3, h = bph & 7;
    const size_t tok0 = (size_t)bp * 512;
    const int q0   = wid * 64;
    const int qcol = h * 64;

    bf16x8 qf[4][2];
    #pragma unroll
    for (int mj = 0; mj < 4; ++mj)
        #pragma unroll
        for (int kf = 0; kf < 2; ++kf)
            qf[mj][kf] = *(const bf16x8*)(qkv + (tok0 + q0 + mj * 16 + l15) * 1536
                                          + qcol + kf * 32 + 8 * lg);

    f32x4 ot[4][4];
    #pragma unroll
    for (int i = 0; i < 4; ++i)
        #pragma unroll
        for (int j = 0; j < 4; ++j)
            ot[i][j] = f32x4{0.f, 0.f, 0.f, 0.f};
    float mrun[4], lrun[4];
    #pragma unroll
    for (int mj = 0; mj < 4; ++mj) { mrun[mj] = -1e30f; lrun[mj] = 0.f; }

    const int sn = t >> 3;
    const int sd = (t & 7) * 8;

    for (int kv0 = 0; kv0 < 512; kv0 += 64) {
        const short* kvrow = qkv + (tok0 + kv0 + sn) * 1536;
        *(bf16x8*)&Kl[sn][sd] = *(const bf16x8*)(kvrow + 512 + qcol + sd);
        bf16x8 vv = *(const bf16x8*)(kvrow + 1024 + qcol + sd);
        #pragma unroll
        for (int i = 0; i < 8; ++i) Vt[sd + i][sn] = vv[i];
        __syncthreads();

        f32x4 st[4][4];
        #pragma unroll
        for (int i = 0; i < 4; ++i)
            #pragma unroll
            for (int j = 0; j < 4; ++j)
                st[i][j] = f32x4{0.f, 0.f, 0.f, 0.f};
        #pragma unroll
        for (int kf = 0; kf < 2; ++kf) {
            #pragma unroll
            for (int ni = 0; ni < 4; ++ni) {
                bf16x8 kfr = *(const bf16x8*)&Kl[ni * 16 + l15][kf * 32 + 8 * lg];
                #pragma unroll
                for (int mj = 0; mj < 4; ++mj)
                    st[ni][mj] = __builtin_amdgcn_mfma_f32_16x16x32_bf16(
                        kfr, qf[mj][kf], st[ni][mj], 0, 0, 0);
            }
        }

        #pragma unroll
        for (int mj = 0; mj < 4; ++mj) {
            float pm = -1e30f;
            #pragma unroll
            for (int ni = 0; ni < 4; ++ni)
                #pragma unroll
                for (int r = 0; r < 4; ++r) {
                    st[ni][mj][r] *= 0.125f;
                    pm = fmaxf(pm, st[ni][mj][r]);
                }
            pm = fmaxf(pm, __shfl_xor(pm, 16));
            pm = fmaxf(pm, __shfl_xor(pm, 32));
            const float mnew = fmaxf(mrun[mj], pm);
            const float fsc  = __expf(mrun[mj] - mnew);
            float ps = 0.f;
            #pragma unroll
            for (int ni = 0; ni < 4; ++ni)
                #pragma unroll
                for (int r = 0; r < 4; ++r) {
                    float e = __expf(st[ni][mj][r] - mnew);
                    st[ni][mj][r] = e;
                    ps += e;
                }
            ps += __shfl_xor(ps, 16);
            ps += __shfl_xor(ps, 32);
            lrun[mj] = lrun[mj] * fsc + ps;
            mrun[mj] = mnew;
            #pragma unroll
            for (int di = 0; di < 4; ++di)
                ot[di][mj] *= fsc;
        }

        #pragma unroll
        for (int ni = 0; ni < 4; ++ni) {
            bf16x4 pb[4];
            #pragma unroll
            for (int mj = 0; mj < 4; ++mj)
                #pragma unroll
                for (int r = 0; r < 4; ++r)
                    pb[mj][r] = (short)f2bf(st[ni][mj][r]);
            #pragma unroll
            for (int di = 0; di < 4; ++di) {
                bf16x4 av = *(const bf16x4*)&Vt[di * 16 + l15][ni * 16 + 4 * lg];
                #pragma unroll
                for (int mj = 0; mj < 4; ++mj)
                    ot[di][mj] = __builtin_amdgcn_mfma_f32_16x16x16bf16_1k(
                        av, pb[mj], ot[di][mj], 0, 0, 0);
            }
        }
        __syncthreads();
    }

    float inv[4];
    #pragma unroll
    for (int mj = 0; mj < 4; ++mj) inv[mj] = 1.f / lrun[mj];
    #pragma unroll
    for (int di = 0; di < 4; ++di)
        #pragma unroll
        for (int mj = 0; mj < 4; ++mj) {
            const size_t tok = tok0 + q0 + mj * 16 + l15;
            const int col = qcol + di * 16 + 4 * lg;
            bf16x4 o4;
            #pragma unroll
            for (int r = 0; r < 4; ++r)
                o4[r] = (short)f2bf(ot[di][mj][r] * inv[mj]);
            *(bf16x4*)(attn_out + tok * 512 + col) = o4;
        }
}

extern "C" void kernel_launch(void* const* d_in, const int* in_sizes, int n_in,
                              void* d_out, int out_size, void* d_ws, size_t ws_size,
                              hipStream_t stream) {
    const float* x    = (const float*)d_in[0];   // [16384][512]
    const float* Wqkv = (const float*)d_in[1];   // [512][1536]
    const float* Wout = (const float*)d_in[2];   // [512][512]
    const float* bout = (const float*)d_in[3];   // [512]
    float* out = (float*)d_out;                  // [16384][512] f32

    char* ws = (char*)d_ws;
    short* qkvb  = (short*)(ws);                 // 48 MB  [16384][1536] bf16
    short* xb    = (short*)(ws + 50331648ull);   // 16 MB  [16384][512]  bf16 (x)
    short* attnb = xb;                           // reuse: xb dead before attn writes
    short* Wqkvt = (short*)(ws + 67108864ull);   // 1.5 MB [1536][512]   bf16
    short* Woutt = (short*)(ws + 68681728ull);   // 0.5 MB [512][512]    bf16

    cvt_x<<<4096, 256, 0, stream>>>(x, xb);
    prep_w<<<3072, 256, 0, stream>>>(Wqkv, Wout, Wqkvt, Woutt);

    dim3 g1(64, 6);    // M=16384, N=1536
    gemm8p<0><<<g1, 512, 0, stream>>>(xb, Wqkvt, qkvb, nullptr, nullptr,
                                      16384, 1536, 512);

    attn_kernel<<<256, 512, 0, stream>>>(qkvb, attnb);

    dim3 g2(64, 2);    // M=16384, N=512
    gemm8p<1><<<g2, 512, 0, stream>>>(attnb, Woutt, nullptr, out, bout,
                                      16384, 512, 512);
}